// Round 6
// baseline (1002.234 us; speedup 1.0000x reference)
//
#include <hip/hip_runtime.h>
#include <math.h>

typedef _Float16 half8 __attribute__((ext_vector_type(8)));
typedef float floatx4 __attribute__((ext_vector_type(4)));
typedef unsigned u32x4v __attribute__((ext_vector_type(4)));
typedef unsigned long long u64;

#define MFMA16(a, b, c) __builtin_amdgcn_mfma_f32_16x16x32_f16((a), (b), (c), 0, 0, 0)
#define AARG __ATOMIC_RELAXED, __HIP_MEMORY_SCOPE_AGENT

static constexpr float C11 = 4.8828125e-4f;          // 2^-11
static constexpr float C22 = 2.384185791015625e-7f;  // 2^-22
static constexpr int LOPG = 128 * 264;               // lo-page offset in ldsWih
static constexpr int SLOTS = 257;                    // deep ring: one slot per step
static constexpr int LSTRIDE = SLOTS * 8 * 128;      // atoms per layer

// Exchange atom: {tag = step (low 32) | h-bits (high 32)} — self-validating.
// Dual-ring: g_local (XCD-L2 mirror, plain store + sc0 load, fast path) and
// g_exch (agent-scope atomics, guaranteed path). Consumers poll 4 local : 1
// agent, so correctness never depends on dispatch placement or cache flags.
__device__ __align__(16) u64 g_exch[2 * LSTRIDE];
__device__ __align__(16) u64 g_local[2 * LSTRIDE];
__device__ _Float16 g_xhi[8388608];  // x hi/lo split planes
__device__ _Float16 g_xlo[8388608];

__global__ __launch_bounds__(256) void zero_k() {
  unsigned i = blockIdx.x * 256 + threadIdx.x;  // grid 2056 = 526336/256
  if (i < 2 * LSTRIDE) {
    g_exch[i] = 0;
    g_local[i] = 0;
  }
}

__device__ __forceinline__ u64 ald(const u64* p) {
  return __hip_atomic_load(p, AARG);
}
__device__ __forceinline__ void ast(u64* p, u64 v) {
  __hip_atomic_store(p, v, AARG);
}
// Local-mirror primitives: plain store (write-through L1 -> lands in own-XCD
// L2); sc0 load (bypass L1, read L2). Visible same-XCD if dispatch is
// round-robin; if not, the agent path below catches it.
__device__ __forceinline__ void st_loc(u64* p, u64 v) {
  asm volatile("global_store_dwordx2 %0, %1, off" ::"v"(p), "v"(v) : "memory");
}
__device__ __forceinline__ void ld4_loc(const u64* p, u64& a, u64& b) {
  u32x4v t;
  asm volatile("global_load_dwordx4 %0, %1, off sc0\n\ts_waitcnt vmcnt(0)"
               : "=&v"(t) : "v"(p) : "memory");
  a = ((u64)t.y << 32) | t.x;
  b = ((u64)t.w << 32) | t.z;
}
__device__ __forceinline__ void ld8_loc(const u64* p, u64 (&w)[8]) {
  asm volatile(
      "global_load_dwordx2 %0, %8, off sc0\n\t"
      "global_load_dwordx2 %1, %8, off offset:128 sc0\n\t"
      "global_load_dwordx2 %2, %8, off offset:256 sc0\n\t"
      "global_load_dwordx2 %3, %8, off offset:384 sc0\n\t"
      "global_load_dwordx2 %4, %8, off offset:512 sc0\n\t"
      "global_load_dwordx2 %5, %8, off offset:640 sc0\n\t"
      "global_load_dwordx2 %6, %8, off offset:768 sc0\n\t"
      "global_load_dwordx2 %7, %8, off offset:896 sc0\n\t"
      "s_waitcnt vmcnt(0)"
      : "=&v"(w[0]), "=&v"(w[1]), "=&v"(w[2]), "=&v"(w[3]),
        "=&v"(w[4]), "=&v"(w[5]), "=&v"(w[6]), "=&v"(w[7])
      : "v"(p) : "memory");
}

// f32 -> normal-f16 hi + 2^11-scaled f16 lo (denorm-proof; round-2-verified).
__device__ __forceinline__ void split16(float v, _Float16& hi, _Float16& lo) {
  _Float16 h = (fabsf(v) < 6.103515625e-05f) ? (_Float16)0.0f : (_Float16)v;
  hi = h;
  lo = (_Float16)((v - (float)h) * 2048.0f);
}

__global__ __launch_bounds__(256) void presplit_k(const float* __restrict__ x) {
  int i = (blockIdx.x * 256 + threadIdx.x) * 8;
  floatx4 a = *(const floatx4*)(x + i);
  floatx4 b = *(const floatx4*)(x + i + 4);
  half8 hi, lo;
#pragma unroll
  for (int e = 0; e < 4; ++e) { _Float16 p, q; split16(a[e], p, q); hi[e] = p; lo[e] = q; }
#pragma unroll
  for (int e = 0; e < 4; ++e) { _Float16 p, q; split16(b[e], p, q); hi[4 + e] = p; lo[4 + e] = q; }
  *(half8*)(g_xhi + i) = hi;
  *(half8*)(g_xlo + i) = lo;
}

// One WG = (group g: 16 sequences) x (slice kwg: 32 hidden cols, all 4 gates).
// 8 groups x 8 slices x 2 layers = 128 WGs; g = blockIdx&7 so under
// round-robin dispatch all 16 WGs of a group share one XCD (fast path).
template <int LAYER>
__device__ void scan_body(_Float16* ldsWih, _Float16* lut, unsigned* hwLDS,
                          u64* spikeLDS, const float* __restrict__ wih,
                          const float* __restrict__ whh,
                          const float* __restrict__ bias,
                          float* __restrict__ dout, int g, int kwg) {
  const int tid = threadIdx.x;
  const int lane = tid & 63;
  const int wv = tid >> 6;
  const int m16 = lane & 15;
  const int l16 = lane >> 4;

  u64* exch0 = g_exch;                     // layer-0 agent ring (L1 reads it)
  u64* exchMy = g_exch + LAYER * LSTRIDE;  // own agent ring
  u64* loc0 = g_local;                     // layer-0 local mirror
  u64* locMy = g_local + LAYER * LSTRIDE;  // own local mirror

  // ---- stage W_ih slice into LDS (hi/lo split on the fly) ----
  for (int t = tid; t < 4096; t += 256) {
    int nl = t >> 5, ci = t & 31;
    int grow = (nl >> 5) * 256 + 32 * kwg + (nl & 31);
    const float* src = wih + (size_t)grow * 256 + ci * 8;
    floatx4 v0 = *(const floatx4*)src;
    floatx4 v1 = *(const floatx4*)(src + 4);
    half8 hi, lo;
#pragma unroll
    for (int e = 0; e < 4; ++e) { _Float16 p, q; split16(v0[e], p, q); hi[e] = p; lo[e] = q; }
#pragma unroll
    for (int e = 0; e < 4; ++e) { _Float16 p, q; split16(v1[e], p, q); hi[4 + e] = p; lo[4 + e] = q; }
    *(half8*)(ldsWih + (size_t)nl * 264 + ci * 8) = hi;
    *(half8*)(ldsWih + LOPG + (size_t)nl * 264 + ci * 8) = lo;
  }
#pragma unroll
  for (int e = 0; e < 8; ++e)
    lut[tid * 8 + e] = ((tid >> e) & 1) ? (_Float16)1.0f : (_Float16)0.0f;

  // ---- persistent W_hh fragments in VGPRs ----
  half8 BhhH[2][8], BhhL[2][8];
#pragma unroll
  for (int t2 = 0; t2 < 2; ++t2) {
    int grow = wv * 256 + 32 * kwg + t2 * 16 + m16;
#pragma unroll
    for (int q = 0; q < 8; ++q) {
      const float* src = whh + (size_t)grow * 256 + 32 * q + 8 * l16;
      floatx4 v0 = *(const floatx4*)src;
      floatx4 v1 = *(const floatx4*)(src + 4);
      half8 hi, lo;
#pragma unroll
      for (int e = 0; e < 4; ++e) { _Float16 p, q2; split16(v0[e], p, q2); hi[e] = p; lo[e] = q2; }
#pragma unroll
      for (int e = 0; e < 4; ++e) { _Float16 p, q2; split16(v1[e], p, q2); hi[4 + e] = p; lo[4 + e] = q2; }
      BhhH[t2][q] = hi;
      BhhL[t2][q] = lo;
    }
  }

  float bl[2];
#pragma unroll
  for (int t2 = 0; t2 < 2; ++t2) bl[t2] = bias[wv * 256 + 32 * kwg + t2 * 16 + m16];

  floatx4 A0a[2], A1a[2], A2a[2], A0b[2], A1b[2], A2b[2];
  half8 xrh[8], xrl[8];  // LAYER0 input fragments
  unsigned xw[8];        // LAYER1 bit-words
  u64 cst = 0;
  int polls = 0;
  const int POLL_MAX = 1 << 22;  // bail visibly, never hang

  auto issue_x = [&](int ln) {  // LAYER 0 only
    size_t base = ((size_t)ln * 128 + 16 * g + m16) * 256 + 8 * l16;
#pragma unroll
    for (int q = 0; q < 8; ++q) {
      xrh[q] = *(const half8*)(g_xhi + base + 32 * q);
      xrl[q] = *(const half8*)(g_xlo + base + 32 * q);
    }
  };

  // LAYER 1: self-tagged input words; 4 local tries per 1 agent try.
  auto read_xw = [&](int tag) {
    const u64* pl = loc0 + (size_t)tag * 1024 + g * 128 + m16;
    const u64* pa = exch0 + (size_t)tag * 1024 + g * 128 + m16;
    u64 v[8];
    for (;;) {
      bool got = false;
#pragma unroll 1
      for (int r = 0; r < 4 && !got; ++r) {
        ld8_loc(pl, v);
        bool ok = true;
#pragma unroll
        for (int q = 0; q < 8; ++q) ok = ok && ((unsigned)v[q] == (unsigned)tag);
        got = __all(ok);
      }
      if (got) break;
#pragma unroll
      for (int q = 0; q < 8; ++q) v[q] = ald(pa + q * 16);
      bool ok = true;
#pragma unroll
      for (int q = 0; q < 8; ++q) ok = ok && ((unsigned)v[q] == (unsigned)tag);
      if (__all(ok)) break;
      if ((polls += 5) > POLL_MAX) break;
    }
#pragma unroll
    for (int q = 0; q < 8; ++q) xw[q] = (unsigned)(v[q] >> 32);
  };

  auto ih_compute = [&](floatx4(&A0)[2], floatx4(&A1)[2], floatx4(&A2)[2]) {
    floatx4 zz = {0.f, 0.f, 0.f, 0.f};
    A0[0] = A0[1] = zz; A1[0] = A1[1] = zz; A2[0] = A2[1] = zz;
#pragma unroll
    for (int q = 0; q < 8; ++q) {
      half8 ah, al;
      if constexpr (LAYER == 0) {
        ah = xrh[q];
        al = xrl[q];
      } else {
        unsigned byt = (xw[q] >> (8 * l16)) & 0xFFu;
        ah = *(const half8*)(lut + byt * 8);
      }
#pragma unroll
      for (int t2 = 0; t2 < 2; ++t2) {
        int rbase = (32 * wv + t2 * 16 + m16) * 264 + 32 * q + 8 * l16;
        half8 whi = *(const half8*)(ldsWih + rbase);
        half8 wlo = *(const half8*)(ldsWih + LOPG + rbase);
        A0[t2] = MFMA16(ah, whi, A0[t2]);
        A1[t2] = MFMA16(ah, wlo, A1[t2]);
        if constexpr (LAYER == 0) {
          A1[t2] = MFMA16(al, whi, A1[t2]);
          A2[t2] = MFMA16(al, wlo, A2[t2]);
        }
      }
    }
  };

  // 32 h-bits of sequence s=lane (<16), assembled from this wave's per-thread v
  auto gather16 = [&](u64 v) -> unsigned {
    unsigned a0 = __shfl((unsigned)v, lane & 3);
    unsigned a1 = __shfl((unsigned)(v >> 32), lane & 3);
    unsigned b0 = __shfl((unsigned)v, 4 + (lane & 3));
    unsigned b1 = __shfl((unsigned)(v >> 32), 4 + (lane & 3));
    u64 A = ((u64)a1 << 32) | a0;
    u64 B = ((u64)b1 << 32) | b0;
    int sh = 16 * ((lane & 15) >> 2);
    return (unsigned)((A >> sh) & 0xFFFFull) |
           ((unsigned)((B >> sh) & 0xFFFFull) << 16);
  };

  auto step_body = [&](int l, floatx4(&u0)[2], floatx4(&u1)[2], floatx4(&u2)[2],
                       floatx4(&f0)[2], floatx4(&f1)[2], floatx4(&f2)[2]) {
    // (1) IH for step l+1 (cross-layer wait lives here for L1)
    if (l < 255) {
      if constexpr (LAYER == 1) read_xw(l + 2);
      ih_compute(f0, f1, f2);
      if constexpr (LAYER == 0) issue_x(l + 2 > 255 ? 255 : l + 2);
    }
    // (2) own-ring wait + read for h(l), wave0 only; 4 local : 1 agent tries
    if (wv == 0 && l > 0) {
      const u64* pl = locMy + (size_t)l * 1024 + g * 128 + 2 * lane;
      const u64* pa = exchMy + (size_t)l * 1024 + g * 128 + 2 * lane;
      u64 v0, v1;
      for (;;) {
        bool got = false;
#pragma unroll 1
        for (int r = 0; r < 4 && !got; ++r) {
          ld4_loc(pl, v0, v1);
          got = __all(((unsigned)v0 == (unsigned)l) && ((unsigned)v1 == (unsigned)l));
        }
        if (got) break;
        v0 = ald(pa);
        v1 = ald(pa + 1);
        if (__all(((unsigned)v0 == (unsigned)l) && ((unsigned)v1 == (unsigned)l))) break;
        if ((polls += 5) > POLL_MAX) break;
      }
      hwLDS[2 * lane] = (unsigned)(v0 >> 32);
      hwLDS[2 * lane + 1] = (unsigned)(v1 >> 32);
    }
    __syncthreads();  // A: hwLDS ready
    // (3) recurrent matvec from VGPR-resident W_hh
    floatx4 ac0 = u0[0], ac1 = u0[1], bc0 = u1[0], bc1 = u1[1];
    if (l > 0) {
#pragma unroll
      for (int q = 0; q < 8; ++q) {
        unsigned mw = hwLDS[q * 16 + m16];
        unsigned byt = (mw >> (8 * l16)) & 0xFFu;
        half8 af = *(const half8*)(lut + byt * 8);
        ac0 = MFMA16(af, BhhH[0][q], ac0);
        ac1 = MFMA16(af, BhhH[1][q], ac1);
        bc0 = MFMA16(af, BhhL[0][q], bc0);
        bc1 = MFMA16(af, BhhL[1][q], bc1);
      }
    }
    // (4) gates -> spikes -> bitwise c,h update
    u64 bal[2][4];
#pragma unroll
    for (int r = 0; r < 4; ++r) {
      float p0 = ac0[r] + bl[0] + C11 * bc0[r] + C22 * u2[0][r];
      float p1 = ac1[r] + bl[1] + C11 * bc1[r] + C22 * u2[1][r];
      bal[0][r] = __ballot(p0 >= 0.0f);
      bal[1][r] = __ballot(p1 >= 0.0f);
    }
    if (lane == 0) {
#pragma unroll
      for (int t2 = 0; t2 < 2; ++t2)
#pragma unroll
        for (int r = 0; r < 4; ++r) spikeLDS[wv * 8 + t2 * 4 + r] = bal[t2][r];
    }
    __syncthreads();  // B: spikes ready
    {
      int idx = lane & 7;
      u64 iS = spikeLDS[idx], fS = spikeLDS[8 + idx];
      u64 gS = spikeLDS[16 + idx], oS = spikeLDS[24 + idx];
      cst = (fS & cst) | (iS & gS);  // c = min(f*c+i*g, 1) exactly
    }
    u64 hS = spikeLDS[24 + (lane & 7)] & cst;  // h = o*c
    // (5) wave0: dual-publish {h | tag l+1}; wave1: dout; wave2: final states
    if (wv == 0) {
      unsigned hu = gather16(hS);
      if (lane < 16) {
        u64 atom = ((u64)hu << 32) | (unsigned)(l + 1);
        size_t off = (size_t)(l + 1) * 1024 + g * 128 + kwg * 16 + lane;
        st_loc(locMy + off, atom);  // fast path (own-XCD L2)
        ast(exchMy + off, atom);    // guaranteed path (LLC)
      }
    }
    if (LAYER == 1 && wv == 1) {
      unsigned hu = gather16(hS);
      if (lane < 16) {
        float* frow = dout + ((size_t)l * 128 + 16 * g + lane) * 256 + 32 * kwg;
#pragma unroll
        for (int c4 = 0; c4 < 8; ++c4) {
          floatx4 v;
#pragma unroll
          for (int j = 0; j < 4; ++j) v[j] = ((hu >> (c4 * 4 + j)) & 1) ? 1.0f : 0.0f;
          *(floatx4*)(frow + c4 * 4) = v;
        }
      }
    }
    if (l == 255 && wv == 2) {
      unsigned hu = gather16(hS);
      unsigned cu = gather16(cst);
      if (lane < 16) {
        float* shp = dout + 8388608 + LAYER * 32768 +
                     (size_t)(16 * g + lane) * 256 + 32 * kwg;
        float* scp = shp + 65536;
#pragma unroll
        for (int c4 = 0; c4 < 8; ++c4) {
          floatx4 vh, vc;
#pragma unroll
          for (int j = 0; j < 4; ++j) {
            vh[j] = ((hu >> (c4 * 4 + j)) & 1) ? 1.0f : 0.0f;
            vc[j] = ((cu >> (c4 * 4 + j)) & 1) ? 1.0f : 0.0f;
          }
          *(floatx4*)(shp + c4 * 4) = vh;
          *(floatx4*)(scp + c4 * 4) = vc;
        }
      }
    }
  };

  // ---- prologue ----
  if constexpr (LAYER == 0) {
    issue_x(0);
    __syncthreads();  // ldsWih + lut ready
    ih_compute(A0a, A1a, A2a);
    issue_x(1);
  } else {
    __syncthreads();  // ldsWih + lut ready
    read_xw(1);       // h0(0)
    ih_compute(A0a, A1a, A2a);
  }

#pragma unroll 1
  for (int l = 0; l < 256; l += 2) {
    step_body(l, A0a, A1a, A2a, A0b, A1b, A2b);
    step_body(l + 1, A0b, A1b, A2b, A0a, A1a, A2a);
  }
}

__global__ __launch_bounds__(256, 1) void spike_scan(
    const float* __restrict__ wih0, const float* __restrict__ whh0,
    const float* __restrict__ b0, const float* __restrict__ wih1,
    const float* __restrict__ whh1, const float* __restrict__ b1,
    float* __restrict__ dout) {
  __shared__ __align__(16) _Float16 ldsWih[2 * 128 * 264];
  __shared__ __align__(16) _Float16 lut[256 * 8];
  __shared__ unsigned hwLDS[128];
  __shared__ u64 spikeLDS[32];

  int bi = blockIdx.x;
  int g = bi & 7;
  int kwg = (bi >> 3) & 7;
  if ((bi >> 6) == 0)
    scan_body<0>(ldsWih, lut, hwLDS, spikeLDS, wih0, whh0, b0, dout, g, kwg);
  else
    scan_body<1>(ldsWih, lut, hwLDS, spikeLDS, wih1, whh1, b1, dout, g, kwg);
}

extern "C" void kernel_launch(void* const* d_in, const int* in_sizes, int n_in,
                              void* d_out, int out_size, void* d_ws, size_t ws_size,
                              hipStream_t stream) {
  (void)in_sizes; (void)n_in; (void)out_size; (void)d_ws; (void)ws_size;
  const float* x = (const float*)d_in[0];
  const float* wih0 = (const float*)d_in[1];
  const float* whh0 = (const float*)d_in[2];
  const float* b0 = (const float*)d_in[3];
  const float* wih1 = (const float*)d_in[4];
  const float* whh1 = (const float*)d_in[5];
  const float* b1 = (const float*)d_in[6];
  float* dout = (float*)d_out;

  zero_k<<<2056, 256, 0, stream>>>();
  presplit_k<<<4096, 256, 0, stream>>>(x);
  spike_scan<<<128, 256, 0, stream>>>(wih0, whh0, b0, wih1, whh1, b1, dout);
}

// Round 7
// 958.542 us; speedup vs baseline: 1.0456x; 1.0456x over previous
//
#include <hip/hip_runtime.h>
#include <math.h>

typedef _Float16 half8 __attribute__((ext_vector_type(8)));
typedef float floatx4 __attribute__((ext_vector_type(4)));
typedef unsigned long long u64;

#define MFMA16(a, b, c) __builtin_amdgcn_mfma_f32_16x16x32_f16((a), (b), (c), 0, 0, 0)
#define AARG __ATOMIC_RELAXED, __HIP_MEMORY_SCOPE_AGENT

static constexpr float C11 = 4.8828125e-4f;          // 2^-11
static constexpr float C22 = 2.384185791015625e-7f;  // 2^-22
static constexpr int LOPG = 128 * 264;               // lo-page offset in ldsWih
static constexpr int SLOTS = 257;                    // deep ring: one slot per step
static constexpr int LSTRIDE = SLOTS * 8 * 128;      // atoms per layer

// Exchange atom: {tag = step (low 32) | h-bits (high 32)} — self-validating.
// Deep ring (slot == tag): every slot written once per launch -> no
// backpressure, no wrap hazard, L0 free to run ahead of L1.
__device__ u64 g_exch[2 * LSTRIDE];
__device__ _Float16 g_xhi[8388608];  // x hi/lo split planes
__device__ _Float16 g_xlo[8388608];

__global__ __launch_bounds__(256) void zero_k() {
  unsigned i = blockIdx.x * 256 + threadIdx.x;  // grid 2056 = 526336/256
  if (i < 2 * LSTRIDE) g_exch[i] = 0;
}

__device__ __forceinline__ u64 ald(const u64* p) {
  return __hip_atomic_load(p, AARG);
}
__device__ __forceinline__ void ast(u64* p, u64 v) {
  __hip_atomic_store(p, v, AARG);
}

// f32 -> normal-f16 hi + 2^11-scaled f16 lo (denorm-proof; round-2-verified).
__device__ __forceinline__ void split16(float v, _Float16& hi, _Float16& lo) {
  _Float16 h = (fabsf(v) < 6.103515625e-05f) ? (_Float16)0.0f : (_Float16)v;
  hi = h;
  lo = (_Float16)((v - (float)h) * 2048.0f);
}

__global__ __launch_bounds__(256) void presplit_k(const float* __restrict__ x) {
  int i = (blockIdx.x * 256 + threadIdx.x) * 8;
  floatx4 a = *(const floatx4*)(x + i);
  floatx4 b = *(const floatx4*)(x + i + 4);
  half8 hi, lo;
#pragma unroll
  for (int e = 0; e < 4; ++e) { _Float16 p, q; split16(a[e], p, q); hi[e] = p; lo[e] = q; }
#pragma unroll
  for (int e = 0; e < 4; ++e) { _Float16 p, q; split16(b[e], p, q); hi[4 + e] = p; lo[4 + e] = q; }
  *(half8*)(g_xhi + i) = hi;
  *(half8*)(g_xlo + i) = lo;
}

// One WG = (group g: 16 sequences) x (slice kwg: 32 hidden cols, all 4 gates).
// 8 groups x 8 slices x 2 layers = 128 WGs; wave wv = gate type.
template <int LAYER>
__device__ void scan_body(_Float16* ldsWih, _Float16* lut, unsigned* hwLDS,
                          u64* spikeLDS, const float* __restrict__ wih,
                          const float* __restrict__ whh,
                          const float* __restrict__ bias,
                          float* __restrict__ dout, int g, int kwg) {
  const int tid = threadIdx.x;
  const int lane = tid & 63;
  const int wv = tid >> 6;
  const int m16 = lane & 15;
  const int l16 = lane >> 4;

  u64* exch0 = g_exch;                     // layer-0 ring (L1 reads it)
  u64* exchMy = g_exch + LAYER * LSTRIDE;  // own ring

  // ---- stage W_ih slice into LDS (hi/lo split on the fly) ----
  for (int t = tid; t < 4096; t += 256) {
    int nl = t >> 5, ci = t & 31;
    int grow = (nl >> 5) * 256 + 32 * kwg + (nl & 31);
    const float* src = wih + (size_t)grow * 256 + ci * 8;
    floatx4 v0 = *(const floatx4*)src;
    floatx4 v1 = *(const floatx4*)(src + 4);
    half8 hi, lo;
#pragma unroll
    for (int e = 0; e < 4; ++e) { _Float16 p, q; split16(v0[e], p, q); hi[e] = p; lo[e] = q; }
#pragma unroll
    for (int e = 0; e < 4; ++e) { _Float16 p, q; split16(v1[e], p, q); hi[4 + e] = p; lo[4 + e] = q; }
    *(half8*)(ldsWih + (size_t)nl * 264 + ci * 8) = hi;
    *(half8*)(ldsWih + LOPG + (size_t)nl * 264 + ci * 8) = lo;
  }
#pragma unroll
  for (int e = 0; e < 8; ++e)
    lut[tid * 8 + e] = ((tid >> e) & 1) ? (_Float16)1.0f : (_Float16)0.0f;

  // ---- persistent W_hh fragments in VGPRs ----
  half8 BhhH[2][8], BhhL[2][8];
#pragma unroll
  for (int t2 = 0; t2 < 2; ++t2) {
    int grow = wv * 256 + 32 * kwg + t2 * 16 + m16;
#pragma unroll
    for (int q = 0; q < 8; ++q) {
      const float* src = whh + (size_t)grow * 256 + 32 * q + 8 * l16;
      floatx4 v0 = *(const floatx4*)src;
      floatx4 v1 = *(const floatx4*)(src + 4);
      half8 hi, lo;
#pragma unroll
      for (int e = 0; e < 4; ++e) { _Float16 p, q2; split16(v0[e], p, q2); hi[e] = p; lo[e] = q2; }
#pragma unroll
      for (int e = 0; e < 4; ++e) { _Float16 p, q2; split16(v1[e], p, q2); hi[4 + e] = p; lo[4 + e] = q2; }
      BhhH[t2][q] = hi;
      BhhL[t2][q] = lo;
    }
  }

  float bl[2];
#pragma unroll
  for (int t2 = 0; t2 < 2; ++t2) bl[t2] = bias[wv * 256 + 32 * kwg + t2 * 16 + m16];

  floatx4 A0a[2], A1a[2], A2a[2], A0b[2], A1b[2], A2b[2];
  half8 xrh[8], xrl[8];  // LAYER0 input fragments
  u64 xwA[8];            // LAYER1 early-issued input atoms (in flight ~1 step)
  unsigned xw[8];        // LAYER1 validated bit-words
  u64 cst = 0;
  int polls = 0;
  const int POLL_MAX = 1 << 22;  // bail visibly, never hang

  auto issue_x = [&](int ln) {  // LAYER 0 only
    size_t base = ((size_t)ln * 128 + 16 * g + m16) * 256 + 8 * l16;
#pragma unroll
    for (int q = 0; q < 8; ++q) {
      xrh[q] = *(const half8*)(g_xhi + base + 32 * q);
      xrl[q] = *(const half8*)(g_xlo + base + 32 * q);
    }
  };

  // LAYER 1: fire-and-forget loads for tag (consumed one full step later).
  auto issue_xw = [&](int tag) {
    const u64* page = exch0 + (size_t)tag * 1024 + g * 128 + m16;
#pragma unroll
    for (int q = 0; q < 8; ++q) xwA[q] = ald(page + q * 16);
  };

  // LAYER 1: validate the early-issued atoms; fallback poll if stale.
  auto consume_xw = [&](int tag) {
    bool ok = true;
#pragma unroll
    for (int q = 0; q < 8; ++q) ok = ok && ((unsigned)xwA[q] == (unsigned)tag);
    if (!__all(ok)) {
      const u64* page = exch0 + (size_t)tag * 1024 + g * 128 + m16;
      for (;;) {
#pragma unroll
        for (int q = 0; q < 8; ++q) xwA[q] = ald(page + q * 16);
        bool k2 = true;
#pragma unroll
        for (int q = 0; q < 8; ++q) k2 = k2 && ((unsigned)xwA[q] == (unsigned)tag);
        if (__all(k2)) break;
        if (++polls > POLL_MAX) break;
      }
    }
#pragma unroll
    for (int q = 0; q < 8; ++q) xw[q] = (unsigned)(xwA[q] >> 32);
  };

  auto ih_compute = [&](floatx4(&A0)[2], floatx4(&A1)[2], floatx4(&A2)[2]) {
    floatx4 zz = {0.f, 0.f, 0.f, 0.f};
    A0[0] = A0[1] = zz; A1[0] = A1[1] = zz; A2[0] = A2[1] = zz;
#pragma unroll
    for (int q = 0; q < 8; ++q) {
      half8 ah, al;
      if constexpr (LAYER == 0) {
        ah = xrh[q];
        al = xrl[q];
      } else {
        unsigned byt = (xw[q] >> (8 * l16)) & 0xFFu;
        ah = *(const half8*)(lut + byt * 8);
      }
#pragma unroll
      for (int t2 = 0; t2 < 2; ++t2) {
        int rbase = (32 * wv + t2 * 16 + m16) * 264 + 32 * q + 8 * l16;
        half8 whi = *(const half8*)(ldsWih + rbase);
        half8 wlo = *(const half8*)(ldsWih + LOPG + rbase);
        A0[t2] = MFMA16(ah, whi, A0[t2]);
        A1[t2] = MFMA16(ah, wlo, A1[t2]);
        if constexpr (LAYER == 0) {
          A1[t2] = MFMA16(al, whi, A1[t2]);
          A2[t2] = MFMA16(al, wlo, A2[t2]);
        }
      }
    }
  };

  // 32 h-bits of sequence s=lane (<16), assembled from this wave's per-thread v
  auto gather16 = [&](u64 v) -> unsigned {
    unsigned a0 = __shfl((unsigned)v, lane & 3);
    unsigned a1 = __shfl((unsigned)(v >> 32), lane & 3);
    unsigned b0 = __shfl((unsigned)v, 4 + (lane & 3));
    unsigned b1 = __shfl((unsigned)(v >> 32), 4 + (lane & 3));
    u64 A = ((u64)a1 << 32) | a0;
    u64 B = ((u64)b1 << 32) | b0;
    int sh = 16 * ((lane & 15) >> 2);
    return (unsigned)((A >> sh) & 0xFFFFull) |
           ((unsigned)((B >> sh) & 0xFFFFull) << 16);
  };

  auto step_body = [&](int l, floatx4(&u0)[2], floatx4(&u1)[2], floatx4(&u2)[2],
                       floatx4(&f0)[2], floatx4(&f1)[2], floatx4(&f2)[2]) {
    // (1) IH for step l+1; L1 consumes early atoms (zero-wait in steady state)
    // and immediately re-issues for the step after next.
    if (l < 255) {
      if constexpr (LAYER == 1) {
        consume_xw(l + 2);
        if (l <= 253) issue_xw(l + 3);
      }
      ih_compute(f0, f1, f2);
      if constexpr (LAYER == 0) issue_x(l + 2 > 255 ? 255 : l + 2);
    }
    // (2) own-ring wait for h(l), wave0; depth-2 pipelined probes
    if (wv == 0 && l > 0) {
      const u64* pa = exchMy + (size_t)l * 1024 + g * 128 + 2 * lane;
      u64 v0 = ald(pa), v1 = ald(pa + 1);
      for (;;) {
        u64 n0 = ald(pa), n1 = ald(pa + 1);  // next probe already in flight
        if (__all(((unsigned)v0 == (unsigned)l) && ((unsigned)v1 == (unsigned)l)))
          break;
        v0 = n0;
        v1 = n1;
        if (++polls > POLL_MAX) break;
      }
      hwLDS[2 * lane] = (unsigned)(v0 >> 32);
      hwLDS[2 * lane + 1] = (unsigned)(v1 >> 32);
    }
    __syncthreads();  // A: hwLDS ready
    // (3) recurrent matvec from VGPR-resident W_hh
    floatx4 ac0 = u0[0], ac1 = u0[1], bc0 = u1[0], bc1 = u1[1];
    if (l > 0) {
#pragma unroll
      for (int q = 0; q < 8; ++q) {
        unsigned mw = hwLDS[q * 16 + m16];
        unsigned byt = (mw >> (8 * l16)) & 0xFFu;
        half8 af = *(const half8*)(lut + byt * 8);
        ac0 = MFMA16(af, BhhH[0][q], ac0);
        ac1 = MFMA16(af, BhhH[1][q], ac1);
        bc0 = MFMA16(af, BhhL[0][q], bc0);
        bc1 = MFMA16(af, BhhL[1][q], bc1);
      }
    }
    // (4) gates -> spikes -> bitwise c,h update
    u64 bal[2][4];
#pragma unroll
    for (int r = 0; r < 4; ++r) {
      float p0 = ac0[r] + bl[0] + C11 * bc0[r] + C22 * u2[0][r];
      float p1 = ac1[r] + bl[1] + C11 * bc1[r] + C22 * u2[1][r];
      bal[0][r] = __ballot(p0 >= 0.0f);
      bal[1][r] = __ballot(p1 >= 0.0f);
    }
    if (lane == 0) {
#pragma unroll
      for (int t2 = 0; t2 < 2; ++t2)
#pragma unroll
        for (int r = 0; r < 4; ++r) spikeLDS[wv * 8 + t2 * 4 + r] = bal[t2][r];
    }
    __syncthreads();  // B: spikes ready
    {
      int idx = lane & 7;
      u64 iS = spikeLDS[idx], fS = spikeLDS[8 + idx];
      u64 gS = spikeLDS[16 + idx], oS = spikeLDS[24 + idx];
      cst = (fS & cst) | (iS & gS);  // c = min(f*c+i*g, 1) exactly
    }
    u64 hS = spikeLDS[24 + (lane & 7)] & cst;  // h = o*c
    // (5) wave1 publishes (wave0 proceeds to next step); wave2 dout; wave3 states
    if (wv == 1) {
      unsigned hu = gather16(hS);
      if (lane < 16)
        ast(exchMy + (size_t)(l + 1) * 1024 + g * 128 + kwg * 16 + lane,
            ((u64)hu << 32) | (unsigned)(l + 1));
    }
    if (LAYER == 1 && wv == 2) {
      unsigned hu = gather16(hS);
      if (lane < 16) {
        float* frow = dout + ((size_t)l * 128 + 16 * g + lane) * 256 + 32 * kwg;
#pragma unroll
        for (int c4 = 0; c4 < 8; ++c4) {
          floatx4 v;
#pragma unroll
          for (int j = 0; j < 4; ++j) v[j] = ((hu >> (c4 * 4 + j)) & 1) ? 1.0f : 0.0f;
          *(floatx4*)(frow + c4 * 4) = v;
        }
      }
    }
    if (l == 255 && wv == 3) {
      unsigned hu = gather16(hS);
      unsigned cu = gather16(cst);
      if (lane < 16) {
        float* shp = dout + 8388608 + LAYER * 32768 +
                     (size_t)(16 * g + lane) * 256 + 32 * kwg;
        float* scp = shp + 65536;
#pragma unroll
        for (int c4 = 0; c4 < 8; ++c4) {
          floatx4 vh, vc;
#pragma unroll
          for (int j = 0; j < 4; ++j) {
            vh[j] = ((hu >> (c4 * 4 + j)) & 1) ? 1.0f : 0.0f;
            vc[j] = ((cu >> (c4 * 4 + j)) & 1) ? 1.0f : 0.0f;
          }
          *(floatx4*)(shp + c4 * 4) = vh;
          *(floatx4*)(scp + c4 * 4) = vc;
        }
      }
    }
  };

  // ---- prologue ----
  if constexpr (LAYER == 0) {
    issue_x(0);
    __syncthreads();  // ldsWih + lut ready
    ih_compute(A0a, A1a, A2a);
    issue_x(1);
  } else {
    __syncthreads();  // ldsWih + lut ready
    issue_xw(1);
    consume_xw(1);  // h0(0) — genuine wait once at startup
    ih_compute(A0a, A1a, A2a);
    issue_xw(2);
  }

#pragma unroll 1
  for (int l = 0; l < 256; l += 2) {
    step_body(l, A0a, A1a, A2a, A0b, A1b, A2b);
    step_body(l + 1, A0b, A1b, A2b, A0a, A1a, A2a);
  }
}

__global__ __launch_bounds__(256, 1) void spike_scan(
    const float* __restrict__ wih0, const float* __restrict__ whh0,
    const float* __restrict__ b0, const float* __restrict__ wih1,
    const float* __restrict__ whh1, const float* __restrict__ b1,
    float* __restrict__ dout) {
  __shared__ __align__(16) _Float16 ldsWih[2 * 128 * 264];
  __shared__ __align__(16) _Float16 lut[256 * 8];
  __shared__ unsigned hwLDS[128];
  __shared__ u64 spikeLDS[32];

  int bi = blockIdx.x;
  int g = bi & 7;
  int kwg = (bi >> 3) & 7;
  if ((bi >> 6) == 0)
    scan_body<0>(ldsWih, lut, hwLDS, spikeLDS, wih0, whh0, b0, dout, g, kwg);
  else
    scan_body<1>(ldsWih, lut, hwLDS, spikeLDS, wih1, whh1, b1, dout, g, kwg);
}

extern "C" void kernel_launch(void* const* d_in, const int* in_sizes, int n_in,
                              void* d_out, int out_size, void* d_ws, size_t ws_size,
                              hipStream_t stream) {
  (void)in_sizes; (void)n_in; (void)out_size; (void)d_ws; (void)ws_size;
  const float* x = (const float*)d_in[0];
  const float* wih0 = (const float*)d_in[1];
  const float* whh0 = (const float*)d_in[2];
  const float* b0 = (const float*)d_in[3];
  const float* wih1 = (const float*)d_in[4];
  const float* whh1 = (const float*)d_in[5];
  const float* b1 = (const float*)d_in[6];
  float* dout = (float*)d_out;

  zero_k<<<2056, 256, 0, stream>>>();
  presplit_k<<<4096, 256, 0, stream>>>(x);
  spike_scan<<<128, 256, 0, stream>>>(wih0, whh0, b0, wih1, whh1, b1, dout);
}